// Round 11
// baseline (32360.559 us; speedup 1.0000x reference)
//
#include <hip/hip_runtime.h>
#include <math.h>

// Shapes
#define NB   256   // batch N
#define TDIM 87
#define HD   128
#define H3   384
#define NCLS 43

typedef float f32x4 __attribute__((ext_vector_type(4)));
typedef _Float16 f16x8 __attribute__((ext_vector_type(8)));
typedef _Float16 f16x2 __attribute__((ext_vector_type(2)));

__device__ __forceinline__ float sigmoidf_(float x){ return 1.0f/(1.0f + __expf(-x)); }
__device__ __forceinline__ float tanhf_(float x){ return 1.0f - 2.0f/(1.0f + __expf(2.0f*x)); }
__device__ __forceinline__ float lrelu_(float x){ return x > 0.f ? x : 0.01f*x; }

__device__ __forceinline__ float dot4v(float acc, f32x4 a, f32x4 b){
  acc = fmaf(a[0], b[0], acc); acc = fmaf(a[1], b[1], acc);
  acc = fmaf(a[2], b[2], acc); acc = fmaf(a[3], b[3], acc);
  return acc;
}
// 8 f16 MACs via 4x v_dot2_f32_f16 (fp32 accumulate)
__device__ __forceinline__ float dot8h(float acc, f16x8 a, f16x8 b){
  f16x2 a0={a[0],a[1]}, a1={a[2],a[3]}, a2={a[4],a[5]}, a3={a[6],a[7]};
  f16x2 b0={b[0],b[1]}, b1={b[2],b[3]}, b2={b[4],b[5]}, b3={b[6],b[7]};
  acc = __builtin_amdgcn_fdot2(a0,b0,acc,false);
  acc = __builtin_amdgcn_fdot2(a1,b1,acc,false);
  acc = __builtin_amdgcn_fdot2(a2,b2,acc,false);
  acc = __builtin_amdgcn_fdot2(a3,b3,acc,false);
  return acc;
}
__device__ __forceinline__ f16x8 cvt8h(const float* p){
  f16x8 r;
  #pragma unroll
  for (int j=0;j<8;j++) r[j] = (_Float16)p[j];
  return r;
}
// 32-K fp32-weight x f16-h dot (attention phase; h converted per element)
__device__ __forceinline__ float dot32wh(const float4* w, f16x8 x0, f16x8 x1, f16x8 x2, f16x8 x3){
  float acc = 0.f; float4 wv;
  wv=w[0]; acc=fmaf(wv.x,(float)x0[0],acc); acc=fmaf(wv.y,(float)x0[1],acc); acc=fmaf(wv.z,(float)x0[2],acc); acc=fmaf(wv.w,(float)x0[3],acc);
  wv=w[1]; acc=fmaf(wv.x,(float)x0[4],acc); acc=fmaf(wv.y,(float)x0[5],acc); acc=fmaf(wv.z,(float)x0[6],acc); acc=fmaf(wv.w,(float)x0[7],acc);
  wv=w[2]; acc=fmaf(wv.x,(float)x1[0],acc); acc=fmaf(wv.y,(float)x1[1],acc); acc=fmaf(wv.z,(float)x1[2],acc); acc=fmaf(wv.w,(float)x1[3],acc);
  wv=w[3]; acc=fmaf(wv.x,(float)x1[4],acc); acc=fmaf(wv.y,(float)x1[5],acc); acc=fmaf(wv.z,(float)x1[6],acc); acc=fmaf(wv.w,(float)x1[7],acc);
  wv=w[4]; acc=fmaf(wv.x,(float)x2[0],acc); acc=fmaf(wv.y,(float)x2[1],acc); acc=fmaf(wv.z,(float)x2[2],acc); acc=fmaf(wv.w,(float)x2[3],acc);
  wv=w[5]; acc=fmaf(wv.x,(float)x2[4],acc); acc=fmaf(wv.y,(float)x2[5],acc); acc=fmaf(wv.z,(float)x2[6],acc); acc=fmaf(wv.w,(float)x2[7],acc);
  wv=w[6]; acc=fmaf(wv.x,(float)x3[0],acc); acc=fmaf(wv.y,(float)x3[1],acc); acc=fmaf(wv.z,(float)x3[2],acc); acc=fmaf(wv.w,(float)x3[3],acc);
  wv=w[7]; acc=fmaf(wv.x,(float)x3[4],acc); acc=fmaf(wv.y,(float)x3[5],acc); acc=fmaf(wv.z,(float)x3[6],acc); acc=fmaf(wv.w,(float)x3[7],acc);
  return acc;
}

// ---------------- conv1 + relu + maxpool ----------------
__global__ __launch_bounds__(256) void k_conv1(const float* __restrict__ tce,
    const float* __restrict__ w1, const float* __restrict__ b1,
    float* __restrict__ pool1){
  const int n = blockIdx.x, oc = blockIdx.y;
  __shared__ float xs[21*52];
  __shared__ float ws[32];
  __shared__ float cv[17*48];
  const int tid = threadIdx.x;
  const int oh = tid/12, owc = (tid%12)*4;
  const bool act = tid < 204;
  const float bias = b1[oc];
  float acc[4];
  #pragma unroll
  for (int j=0;j<4;j++) acc[j] = bias;
  const float* xin  = tce + (size_t)(n*TDIM)*1050;
  const float* wrow = w1  + (size_t)oc*TDIM*25;
  for (int ic=0; ic<TDIM; ++ic){
    for (int j=tid; j<1050; j+=256){ xs[(j/50)*52 + (j%50)] = xin[(size_t)ic*1050 + j]; }
    if (tid < 25) ws[tid] = wrow[ic*25 + tid];
    __syncthreads();
    if (act){
      float wreg[25];
      #pragma unroll
      for (int u=0;u<25;u++) wreg[u] = ws[u];
      #pragma unroll
      for (int r=0;r<5;r++){
        const float4* xr = (const float4*)&xs[(oh+r)*52 + owc];
        float4 v0 = xr[0], v1 = xr[1];
        float xv[8] = {v0.x,v0.y,v0.z,v0.w,v1.x,v1.y,v1.z,v1.w};
        #pragma unroll
        for (int c=0;c<5;c++){
          float w = wreg[r*5+c];
          #pragma unroll
          for (int j=0;j<4;j++) acc[j] = fmaf(w, xv[c+j], acc[j]);
        }
      }
    }
    __syncthreads();
  }
  if (act){
    #pragma unroll
    for (int j=0;j<4;j++){
      int ow = owc + j;
      if (ow < 46) cv[oh*48 + ow] = fmaxf(acc[j], 0.0f);
    }
  }
  __syncthreads();
  if (tid < 176){
    int ph = tid/22, pw = tid%22;
    float m = -1e30f;
    #pragma unroll
    for (int r=0;r<3;r++)
      #pragma unroll
      for (int c=0;c<3;c++)
        m = fmaxf(m, cv[(2*ph+r)*48 + (2*pw+c)]);
    pool1[((size_t)(n*TDIM+oc))*176 + tid] = m;
  }
}

// ---------------- conv2 + relu + maxpool -> cnn (256,87,8) ----------------
__global__ __launch_bounds__(128) void k_conv2(const float* __restrict__ pool1,
    const float* __restrict__ w2, const float* __restrict__ b2,
    float* __restrict__ cnn){
  const int n = blockIdx.x, oc = blockIdx.y;
  __shared__ float xs[176];
  __shared__ float ws[32];
  __shared__ float cv[72];
  const int tid = threadIdx.x;
  float a = b2[oc];
  const int oh = tid/18, ow = tid%18;
  const float* xin = pool1 + (size_t)n*TDIM*176;
  const float* wr  = w2 + (size_t)oc*TDIM*25;
  for (int ic=0; ic<TDIM; ++ic){
    for (int j=tid; j<176; j+=128) xs[j] = xin[(size_t)ic*176 + j];
    if (tid < 25) ws[tid] = wr[ic*25 + tid];
    __syncthreads();
    if (tid < 72){
      #pragma unroll
      for (int r=0;r<5;r++)
        #pragma unroll
        for (int c=0;c<5;c++)
          a = fmaf(ws[r*5+c], xs[(oh+r)*22 + (ow+c)], a);
    }
    __syncthreads();
  }
  if (tid < 72) cv[tid] = fmaxf(a, 0.0f);
  __syncthreads();
  if (tid < 8){
    float m = -1e30f;
    #pragma unroll
    for (int r=0;r<3;r++)
      #pragma unroll
      for (int c=0;c<3;c++)
        m = fmaxf(m, cv[r*18 + (2*tid+c)]);
    cnn[((size_t)(n*TDIM+oc))*8 + tid] = m;
  }
}

// ---------------- utterance bi-GRU ----------------
__global__ __launch_bounds__(768,3) void k_utt(
    const float* __restrict__ te, const float* __restrict__ cnn,
    const float* __restrict__ wih_f, const float* __restrict__ whh_f,
    const float* __restrict__ bih_f, const float* __restrict__ bhh_f,
    const float* __restrict__ wih_b, const float* __restrict__ whh_b,
    const float* __restrict__ bih_b, const float* __restrict__ bhh_b,
    float* __restrict__ Hall){
  const int bx  = blockIdx.x;
  const int dir = bx & 1;
  const int n   = bx >> 1;
  const int tid = threadIdx.x;
  const int o   = tid >> 1, kh = tid & 1;
  const float* wih = dir ? wih_b : wih_f;
  const float* whh = dir ? whh_b : whh_f;
  const float* bih = dir ? bih_b : bih_f;
  const float* bhh = dir ? bhh_b : bhh_f;
  float wh[64], wi[32];
  { const float4* wp = (const float4*)(whh + (size_t)o*128 + kh*64);
    #pragma unroll
    for (int q=0;q<16;q++){ float4 v=wp[q]; wh[4*q]=v.x; wh[4*q+1]=v.y; wh[4*q+2]=v.z; wh[4*q+3]=v.w; } }
  #pragma unroll
  for (int k=0;k<32;k++){ int c = kh*32 + k; wi[k] = (c < 58) ? wih[(size_t)o*58 + c] : 0.f; }
  const float bI = bih[o], bH = bhh[o];
  __shared__ float h[128];
  __shared__ float xb[64];
  __shared__ float s_rz[256];
  __shared__ float gin_s[128];
  __shared__ float ghn_s[128];
  if (tid < 128) h[tid] = 0.f;
  if (tid < 64)  xb[tid] = 0.f;
  __syncthreads();
  for (int t=0;t<TDIM;++t){
    const int ttt = dir ? (TDIM-1-t) : t;
    if (tid < 50)      xb[tid] = te[((size_t)n*TDIM + ttt)*50 + tid];
    else if (tid < 58) xb[tid] = cnn[((size_t)n*TDIM + ttt)*8 + (tid - 50)];
    __syncthreads();
    float a0=0,a1=0,a2=0,a3=0;
    const float4* hp = (const float4*)&h[kh*64];
    #pragma unroll
    for (int q=0;q<16;q++){ float4 hv=hp[q];
      a0=fmaf(wh[4*q],hv.x,a0); a1=fmaf(wh[4*q+1],hv.y,a1);
      a2=fmaf(wh[4*q+2],hv.z,a2); a3=fmaf(wh[4*q+3],hv.w,a3); }
    float ah = (a0+a1)+(a2+a3);
    float c0=0,c1=0,c2=0,c3=0;
    const float4* xp = (const float4*)&xb[kh*32];
    #pragma unroll
    for (int q=0;q<8;q++){ float4 xv=xp[q];
      c0=fmaf(wi[4*q],xv.x,c0); c1=fmaf(wi[4*q+1],xv.y,c1);
      c2=fmaf(wi[4*q+2],xv.z,c2); c3=fmaf(wi[4*q+3],xv.w,c3); }
    float ai = (c0+c1)+(c2+c3);
    ah += __shfl_xor(ah, 1);
    ai += __shfl_xor(ai, 1);
    if (kh == 0){
      if (o < 256) s_rz[o] = ah + ai + bI + bH;
      else { gin_s[o-256] = ai + bI; ghn_s[o-256] = ah + bH; }
    }
    __syncthreads();
    if (tid < 128){
      float r  = sigmoidf_(s_rz[tid]);
      float z  = sigmoidf_(s_rz[128+tid]);
      float nn = tanhf_(gin_s[tid] + r*ghn_s[tid]);
      h[tid] = (1.f - z)*nn + z*h[tid];
    }
    __syncthreads();
  }
  if (tid < 128) Hall[(size_t)n*256 + dir*128 + tid] = h[tid];
}

// ---------------- prep ----------------
__global__ __launch_bounds__(256) void k_prep(const float* __restrict__ Hall,
    const float* __restrict__ ctx_w1, const float* __restrict__ proj_w,
    float* __restrict__ a_all, float* __restrict__ s_all){
  const int i = blockIdx.x; const int tid = threadIdx.x;
  __shared__ float hr[256];
  __shared__ float red[2];
  hr[tid] = Hall[(size_t)i*256 + tid];
  __syncthreads();
  if (tid < 128){
    const float4* w  = (const float4*)(ctx_w1 + (size_t)tid*256);
    const float4* hp = (const float4*)hr;
    float a0=0,a1=0,a2=0,a3=0;
    #pragma unroll 8
    for (int q=0;q<64;q++){ float4 wv=w[q], hv=hp[q];
      a0=fmaf(wv.x,hv.x,a0); a1=fmaf(wv.y,hv.y,a1); a2=fmaf(wv.z,hv.z,a2); a3=fmaf(wv.w,hv.w,a3); }
    a_all[(size_t)i*128 + tid] = (a0+a1)+(a2+a3);
  } else {
    const int k = tid - 128;
    float p = hr[k]*proj_w[k] + hr[k+128]*proj_w[k+128];
    #pragma unroll
    for (int off=32; off; off>>=1) p += __shfl_xor(p, off);
    if ((tid & 63) == 0) red[(tid-128)>>6] = p;
  }
  __syncthreads();
  if (tid == 0) s_all[i] = red[0] + red[1];
}

// ---------------- ctx scan v11: fp16 dots, 256 threads / 4 waves, 2 rows/thread ----------------
// fp16 re-enables 2-rows/thread (v9's plan): 192 weight halfs = 96 VGPRs pinned (v9's fp32
// version needed 192 VGPRs -> impossible). LDS h as f16: return traffic 256->64 cyc/cell.
// Dots via v_dot2_f32_f16 (fp32 accumulate); running hm stays fp32 (only broadcast copy is f16).
__global__ __launch_bounds__(256,1) void k_ctx(
    const float* __restrict__ cg_wih_f, const float* __restrict__ cg_whh_f,
    const float* __restrict__ cg_bih_f, const float* __restrict__ cg_bhh_f,
    const float* __restrict__ cg_wih_b, const float* __restrict__ cg_whh_b,
    const float* __restrict__ cg_bih_b, const float* __restrict__ cg_bhh_b,
    const float* __restrict__ ctx_w2, const float* __restrict__ ctx_b2,
    const float* __restrict__ ctx_w3, const float* __restrict__ proj_b,
    const float* __restrict__ gx0,
    const float* __restrict__ a_all, const float* __restrict__ s_all,
    float* __restrict__ one_d_g, int* __restrict__ flags,
    float* __restrict__ feats){
  const int blk = blockIdx.x;
  const bool isF = blk < 2;
  const int d   = blk & 1;
  const int tid = threadIdx.x;
  const int p2  = tid >> 2;      // row pair [0,64): rows {p2, p2+64}
  const int kq  = tid & 3;       // K-quarter: 32 values
  const float* whh = isF ? cg_whh_f : cg_whh_b;
  const float* wih = isF ? cg_wih_f : cg_wih_b;
  const float* bih = isF ? cg_bih_f : cg_bih_b;
  const float* bhh = isF ? cg_bhh_f : cg_bhh_b;
  const int rA = p2, rB = p2 + 64;

  // ---- stationary weights: convert fp32->fp16, pin via keep-alive asm (24 f16x8 = 96 VGPR)
  const float* bra = whh + (size_t)(      rA)*128 + kq*32;
  const float* bza = whh + (size_t)(128 + rA)*128 + kq*32;
  const float* bna = whh + (size_t)(256 + rA)*128 + kq*32;
  const float* brb = whh + (size_t)(      rB)*128 + kq*32;
  const float* bzb = whh + (size_t)(128 + rB)*128 + kq*32;
  const float* bnb = whh + (size_t)(256 + rB)*128 + kq*32;
  f16x8 wra0=cvt8h(bra),    wra1=cvt8h(bra+8),  wra2=cvt8h(bra+16), wra3=cvt8h(bra+24);
  f16x8 wza0=cvt8h(bza),    wza1=cvt8h(bza+8),  wza2=cvt8h(bza+16), wza3=cvt8h(bza+24);
  f16x8 wna0=cvt8h(bna),    wna1=cvt8h(bna+8),  wna2=cvt8h(bna+16), wna3=cvt8h(bna+24);
  f16x8 wrb0=cvt8h(brb),    wrb1=cvt8h(brb+8),  wrb2=cvt8h(brb+16), wrb3=cvt8h(brb+24);
  f16x8 wzb0=cvt8h(bzb),    wzb1=cvt8h(bzb+8),  wzb2=cvt8h(bzb+16), wzb3=cvt8h(bzb+24);
  f16x8 wnb0=cvt8h(bnb),    wnb1=cvt8h(bnb+8),  wnb2=cvt8h(bnb+16), wnb3=cvt8h(bnb+24);
  asm volatile("" : "+v"(wra0), "+v"(wra1), "+v"(wra2), "+v"(wra3),
                    "+v"(wza0), "+v"(wza1), "+v"(wza2), "+v"(wza3),
                    "+v"(wna0), "+v"(wna1), "+v"(wna2), "+v"(wna3));
  asm volatile("" : "+v"(wrb0), "+v"(wrb1), "+v"(wrb2), "+v"(wrb3),
                    "+v"(wzb0), "+v"(wzb1), "+v"(wzb2), "+v"(wzb3),
                    "+v"(wnb0), "+v"(wnb1), "+v"(wnb2), "+v"(wnb3));

  // ---- tail scalars (kq==0 lanes), keep-alive blocks remat
  float wirA = wih[rA], wizA = wih[128+rA], winA = wih[256+rA];
  float brA_ = bih[rA]      + bhh[rA];
  float bzA_ = bih[128+rA]  + bhh[128+rA];
  float bnA_ = bih[256+rA];
  float bhnA = bhh[256+rA];
  float wirB = wih[rB], wizB = wih[128+rB], winB = wih[256+rB];
  float brB_ = bih[rB]      + bhh[rB];
  float bzB_ = bih[128+rB]  + bhh[128+rB];
  float bnB_ = bih[256+rB];
  float bhnB = bhh[256+rB];
  float pb   = proj_b[0];
  asm volatile("" : "+v"(wirA), "+v"(wizA), "+v"(winA), "+v"(brA_), "+v"(bzA_),
                    "+v"(bnA_), "+v"(bhnA), "+v"(wirB), "+v"(wizB), "+v"(winB),
                    "+v"(brB_), "+v"(bzB_), "+v"(bnB_), "+v"(bhnB), "+v"(pb));

  __shared__ _Float16 hl16[2][160];  // 4 chunks of 32 halfs, stride 40 (80B -> banks 0/20/8/28), dbuf
  __shared__ float one_d_s[128];
  __shared__ float T_s[160];         // fp32, 8 chunks of 16 floats, stride 20
  __shared__ float S_s[128];
  __shared__ float red_s[2];

  const float* gsrc = gx0 + (size_t)((isF ? 0 : 2) + d)*128;
  float hmA = gsrc[rA], hmB = gsrc[rB];   // fp32 running state (kq==0 lanes)
  if (tid < 128) hl16[0][((tid>>5)*40) + (tid&31)] = (_Float16)gsrc[tid];
  __syncthreads();

  const int chA = ((rA>>5)*40) + (rA&31);
  const int chB = ((rB>>5)*40) + (rB&31);
  const int kb16 = kq*40;                 // half-index base of this thread's K-slice
  const int kbT  = kq*40;                 // float-index base in T_s (2 chunks of 16, stride 20)

  for (int i=0;i<NB;++i){
    if (isF){
      // ---- attention: T = tanh(a_all + h@w2.T + b2); S = T@w3.T; one_d = softmax(S)*s + pb
      {
        const f16x8* hp0 = (const f16x8*)&hl16[0][kb16];
        f16x8 g0=hp0[0], g1=hp0[1], g2=hp0[2], g3=hp0[3];
        const float4* w2a = (const float4*)(ctx_w2 + (size_t)rA*128 + kq*32);
        const float4* w2b = (const float4*)(ctx_w2 + (size_t)rB*128 + kq*32);
        float sa = dot32wh(w2a, g0,g1,g2,g3);
        float sb = dot32wh(w2b, g0,g1,g2,g3);
        sa += __shfl_xor(sa,1); sa += __shfl_xor(sa,2);
        sb += __shfl_xor(sb,1); sb += __shfl_xor(sb,2);
        if (kq == 0){
          T_s[((rA>>4)*20)+(rA&15)] = tanhf_(a_all[(size_t)i*128 + rA] + sa + ctx_b2[rA]);
          T_s[((rB>>4)*20)+(rB&15)] = tanhf_(a_all[(size_t)i*128 + rB] + sb + ctx_b2[rB]);
        }
      }
      __syncthreads();
      {
        const float4* w3a = (const float4*)(ctx_w3 + (size_t)rA*128 + kq*32);
        const float4* w3b = (const float4*)(ctx_w3 + (size_t)rB*128 + kq*32);
        const f32x4* tA = (const f32x4*)&T_s[kbT];
        const f32x4* tB = (const f32x4*)&T_s[kbT+20];
        f32x4 t0=tA[0],t1=tA[1],t2=tA[2],t3=tA[3];
        f32x4 t4=tB[0],t5=tB[1],t6=tB[2],t7=tB[3];
        float sa=0, sb=0;
        #pragma unroll
        for (int q=0;q<4;q++){
          float4 wv = w3a[q];  f32x4 w4 = {wv.x,wv.y,wv.z,wv.w};
          f32x4 tv = (q==0)?t0:(q==1)?t1:(q==2)?t2:t3;
          sa = dot4v(sa, w4, tv);
        }
        #pragma unroll
        for (int q=0;q<4;q++){
          float4 wv = w3a[4+q];  f32x4 w4 = {wv.x,wv.y,wv.z,wv.w};
          f32x4 tv = (q==0)?t4:(q==1)?t5:(q==2)?t6:t7;
          sa = dot4v(sa, w4, tv);
        }
        #pragma unroll
        for (int q=0;q<4;q++){
          float4 wv = w3b[q];  f32x4 w4 = {wv.x,wv.y,wv.z,wv.w};
          f32x4 tv = (q==0)?t0:(q==1)?t1:(q==2)?t2:t3;
          sb = dot4v(sb, w4, tv);
        }
        #pragma unroll
        for (int q=0;q<4;q++){
          float4 wv = w3b[4+q];  f32x4 w4 = {wv.x,wv.y,wv.z,wv.w};
          f32x4 tv = (q==0)?t4:(q==1)?t5:(q==2)?t6:t7;
          sb = dot4v(sb, w4, tv);
        }
        sa += __shfl_xor(sa,1); sa += __shfl_xor(sa,2);
        sb += __shfl_xor(sb,1); sb += __shfl_xor(sb,2);
        if (kq == 0){ S_s[rA] = sa; S_s[rB] = sb; }
      }
      __syncthreads();
      if (tid < 64){
        float m = fmaxf(S_s[tid], S_s[tid+64]);
        #pragma unroll
        for (int off=32; off; off>>=1) m = fmaxf(m, __shfl_xor(m, off));
        if (tid == 0) red_s[0] = m;
      }
      __syncthreads();
      if (tid < 128) S_s[tid] = __expf(S_s[tid] - red_s[0]);
      __syncthreads();
      if (tid < 64){
        float s = S_s[tid] + S_s[tid+64];
        #pragma unroll
        for (int off=32; off; off>>=1) s += __shfl_xor(s, off);
        if (tid == 0) red_s[1] = s;
      }
      __syncthreads();
      if (tid < 128){
        float v = (S_s[tid] / red_s[1]) * s_all[i] + pb;
        one_d_s[tid] = v;
        __hip_atomic_store(&one_d_g[((size_t)d*NB + i)*128 + tid], v,
                           __ATOMIC_RELAXED, __HIP_MEMORY_SCOPE_AGENT);
      }
      __syncthreads();
      if (tid == 0){
        __threadfence();
        __hip_atomic_store(&flags[d], i+1, __ATOMIC_RELEASE, __HIP_MEMORY_SCOPE_AGENT);
      }
    } else {
      if (tid == 0){
        while (__hip_atomic_load(&flags[d], __ATOMIC_ACQUIRE, __HIP_MEMORY_SCOPE_AGENT) < i+1){
          __builtin_amdgcn_s_sleep(8);
        }
      }
      __syncthreads();
      if (tid < 128)
        one_d_s[tid] = __hip_atomic_load(&one_d_g[((size_t)d*NB + i)*128 + tid],
                                         __ATOMIC_RELAXED, __HIP_MEMORY_SCOPE_AGENT);
      __syncthreads();
    }
    // ---- inner GRU: 128 cells, ONE barrier each, f16 dots (fp32 accum), divergent tail
    for (int tc=0; tc<128; ++tc){
      const _Float16* hcur = hl16[tc & 1];
      _Float16*       hnxt = hl16[(tc & 1) ^ 1];
      const f16x8* hp = (const f16x8*)&hcur[kb16];
      f16x8 h0=hp[0], h1=hp[1], h2=hp[2], h3=hp[3];
      float arA=0, azA=0, anA=0, arB=0, azB=0, anB=0;
      arA=dot8h(arA,wra0,h0); arA=dot8h(arA,wra1,h1); arA=dot8h(arA,wra2,h2); arA=dot8h(arA,wra3,h3);
      azA=dot8h(azA,wza0,h0); azA=dot8h(azA,wza1,h1); azA=dot8h(azA,wza2,h2); azA=dot8h(azA,wza3,h3);
      anA=dot8h(anA,wna0,h0); anA=dot8h(anA,wna1,h1); anA=dot8h(anA,wna2,h2); anA=dot8h(anA,wna3,h3);
      arB=dot8h(arB,wrb0,h0); arB=dot8h(arB,wrb1,h1); arB=dot8h(arB,wrb2,h2); arB=dot8h(arB,wrb3,h3);
      azB=dot8h(azB,wzb0,h0); azB=dot8h(azB,wzb1,h1); azB=dot8h(azB,wzb2,h2); azB=dot8h(azB,wzb3,h3);
      anB=dot8h(anB,wnb0,h0); anB=dot8h(anB,wnb1,h1); anB=dot8h(anB,wnb2,h2); anB=dot8h(anB,wnb3,h3);
      arA += __shfl_xor(arA,1); arA += __shfl_xor(arA,2);
      azA += __shfl_xor(azA,1); azA += __shfl_xor(azA,2);
      anA += __shfl_xor(anA,1); anA += __shfl_xor(anA,2);
      arB += __shfl_xor(arB,1); arB += __shfl_xor(arB,2);
      azB += __shfl_xor(azB,1); azB += __shfl_xor(azB,2);
      anB += __shfl_xor(anB,1); anB += __shfl_xor(anB,2);
      if (kq == 0){
        float x = one_d_s[isF ? tc : 127-tc];
        float r  = sigmoidf_(fmaf(x, wirA, brA_) + arA);
        float z  = sigmoidf_(fmaf(x, wizA, bzA_) + azA);
        float nn = tanhf_(fmaf(x, winA, bnA_) + r*(anA + bhnA));
        hmA = (1.f - z)*nn + z*hmA;
        hnxt[chA] = (_Float16)hmA;
        r  = sigmoidf_(fmaf(x, wirB, brB_) + arB);
        z  = sigmoidf_(fmaf(x, wizB, bzB_) + azB);
        nn = tanhf_(fmaf(x, winB, bnB_) + r*(anB + bhnB));
        hmB = (1.f - z)*nn + z*hmB;
        hnxt[chB] = (_Float16)hmB;
      }
      __syncthreads();
    }
    if (kq == 0){
      const int off = isF ? d*128 : 256 + d*128;
      feats[(size_t)i*512 + off + rA] = hmA;
      feats[(size_t)i*512 + off + rB] = hmB;
    }
    __syncthreads();
  }
}

// ---------------- classifier ----------------
__global__ __launch_bounds__(256) void k_cls(const float* __restrict__ feats,
    const float* __restrict__ w1, const float* __restrict__ b1,
    const float* __restrict__ w2, const float* __restrict__ b2,
    const float* __restrict__ w3, const float* __restrict__ b3,
    float* __restrict__ out){
  const int n = blockIdx.x; const int tid = threadIdx.x;
  __shared__ float fr[512];
  __shared__ float h1s[256];
  __shared__ float h2s[128];
  fr[tid]       = feats[(size_t)n*512 + tid];
  fr[tid+256]   = feats[(size_t)n*512 + 256 + tid];
  __syncthreads();
  {
    const float4* w  = (const float4*)(w1 + (size_t)tid*512);
    const float4* fp = (const float4*)fr;
    float a0=0,a1=0,a2=0,a3=0;
    #pragma unroll 8
    for (int q=0;q<128;q++){ float4 wv=w[q], fv=fp[q];
      a0=fmaf(wv.x,fv.x,a0); a1=fmaf(wv.y,fv.y,a1); a2=fmaf(wv.z,fv.z,a2); a3=fmaf(wv.w,fv.w,a3); }
    h1s[tid] = lrelu_(b1[tid] + (a0+a1)+(a2+a3));
  }
  __syncthreads();
  if (tid < 128){
    const float4* w  = (const float4*)(w2 + (size_t)tid*256);
    const float4* fp = (const float4*)h1s;
    float a0=0,a1=0,a2=0,a3=0;
    #pragma unroll 8
    for (int q=0;q<64;q++){ float4 wv=w[q], fv=fp[q];
      a0=fmaf(wv.x,fv.x,a0); a1=fmaf(wv.y,fv.y,a1); a2=fmaf(wv.z,fv.z,a2); a3=fmaf(wv.w,fv.w,a3); }
    h2s[tid] = lrelu_(b2[tid] + (a0+a1)+(a2+a3));
  }
  __syncthreads();
  if (tid < NCLS){
    const float4* w  = (const float4*)(w3 + (size_t)tid*128);
    const float4* fp = (const float4*)h2s;
    float a0=0,a1=0,a2=0,a3=0;
    #pragma unroll 8
    for (int q=0;q<32;q++){ float4 wv=w[q], fv=fp[q];
      a0=fmaf(wv.x,fv.x,a0); a1=fmaf(wv.y,fv.y,a1); a2=fmaf(wv.z,fv.z,a2); a3=fmaf(wv.w,fv.w,a3); }
    out[(size_t)n*NCLS + tid] = b3[tid] + (a0+a1)+(a2+a3);
  }
}

// ---------------- workspace layout (bytes) ----------------
#define OFF_FLAGS  0u
#define OFF_SALL   512u
#define OFF_AALL   2048u
#define OFF_ONED   133632u
#define OFF_HALL   395776u
#define OFF_FEATS  657920u
#define OFF_CNN    1182208u
#define OFF_POOL1  1894912u

extern "C" void kernel_launch(void* const* d_in, const int* in_sizes, int n_in,
                              void* d_out, int out_size, void* d_ws, size_t ws_size,
                              hipStream_t stream){
  const float* te   = (const float*)d_in[0];
  const float* tce  = (const float*)d_in[1];
  const float* c1w  = (const float*)d_in[2];
  const float* c1b  = (const float*)d_in[3];
  const float* c2w  = (const float*)d_in[4];
  const float* c2b  = (const float*)d_in[5];
  const float* uwif = (const float*)d_in[6];
  const float* uwhf = (const float*)d_in[7];
  const float* ubif = (const float*)d_in[8];
  const float* ubhf = (const float*)d_in[9];
  const float* uwib = (const float*)d_in[10];
  const float* uwhb = (const float*)d_in[11];
  const float* ubib = (const float*)d_in[12];
  const float* ubhb = (const float*)d_in[13];
  const float* cw1  = (const float*)d_in[14];
  const float* cw2  = (const float*)d_in[15];
  const float* cb2  = (const float*)d_in[16];
  const float* cw3  = (const float*)d_in[17];
  const float* pw   = (const float*)d_in[18];
  const float* pbb  = (const float*)d_in[19];
  const float* gx0  = (const float*)d_in[20];
  const float* gwif = (const float*)d_in[21];
  const float* gwhf = (const float*)d_in[22];
  const float* gbif = (const float*)d_in[23];
  const float* gbhf = (const float*)d_in[24];
  const float* gwib = (const float*)d_in[25];
  const float* gwhb = (const float*)d_in[26];
  const float* gbib = (const float*)d_in[27];
  const float* gbhb = (const float*)d_in[28];
  const float* clw1 = (const float*)d_in[29];
  const float* clb1 = (const float*)d_in[30];
  const float* clw2 = (const float*)d_in[31];
  const float* clb2 = (const float*)d_in[32];
  const float* clw3 = (const float*)d_in[33];
  const float* clb3 = (const float*)d_in[34];
  float* out = (float*)d_out;
  char* ws = (char*)d_ws;
  int*   flags = (int*)  (ws + OFF_FLAGS);
  float* s_all = (float*)(ws + OFF_SALL);
  float* a_all = (float*)(ws + OFF_AALL);
  float* one_d = (float*)(ws + OFF_ONED);
  float* Hall  = (float*)(ws + OFF_HALL);
  float* feats = (float*)(ws + OFF_FEATS);
  float* cnn   = (float*)(ws + OFF_CNN);
  float* pool1 = (float*)(ws + OFF_POOL1);

  hipMemsetAsync(flags, 0, 64, stream);
  k_conv1<<<dim3(NB, TDIM), 256, 0, stream>>>(tce, c1w, c1b, pool1);
  k_conv2<<<dim3(NB, TDIM), 128, 0, stream>>>(pool1, c2w, c2b, cnn);
  k_utt<<<512, 768, 0, stream>>>(te, cnn, uwif, uwhf, ubif, ubhf,
                                 uwib, uwhb, ubib, ubhb, Hall);
  k_prep<<<NB, 256, 0, stream>>>(Hall, cw1, pw, a_all, s_all);
  k_ctx<<<4, 256, 0, stream>>>(gwif, gwhf, gbif, gbhf, gwib, gwhb, gbib, gbhb,
                               cw2, cb2, cw3, pbb, gx0, a_all, s_all,
                               one_d, flags, feats);
  k_cls<<<NB, 256, 0, stream>>>(feats, clw1, clb1, clw2, clb2, clw3, clb3, out);
}